// Round 8
// baseline (829.508 us; speedup 1.0000x reference)
//
#include <hip/hip_runtime.h>
#include <hip/hip_bf16.h>

#define NN 50000
#define EE 800000
#define DD 128

typedef __attribute__((ext_vector_type(8))) short bf16x8;
typedef __attribute__((ext_vector_type(2))) short s16x2;
typedef __attribute__((ext_vector_type(4))) float f32x4;

__device__ __forceinline__ short f2bf(float f) {
    __hip_bfloat16 h = __float2bfloat16(f);
    return __builtin_bit_cast(short, h);
}

__device__ __forceinline__ float bf2f(short s) {
    unsigned int u = ((unsigned int)(unsigned short)s) << 16;
    return __builtin_bit_cast(float, u);
}

__device__ __forceinline__ float fast_silu(float x) {
    return x / (1.0f + __expf(-x));
}

// ---- prep: h->bf16 + zero agg(bf16) (blocks 0..6249), pack weights, w1c bf16 ----
__global__ void prep_kernel(const float* __restrict__ h, unsigned short* __restrict__ hp,
                            ushort4* __restrict__ aggz,
                            const float* __restrict__ W1, const float* __restrict__ W2,
                            const float* __restrict__ U1, const float* __restrict__ U2,
                            unsigned short* __restrict__ packs,
                            unsigned short* __restrict__ w1c_out) {
    if (blockIdx.x < 6250) {
        int t = blockIdx.x * blockDim.x + threadIdx.x;   // 1.6M threads exactly
        float4 v = ((const float4*)h)[t];
        ushort4 o;
        o.x = (unsigned short)f2bf(v.x);
        o.y = (unsigned short)f2bf(v.y);
        o.z = (unsigned short)f2bf(v.z);
        o.w = (unsigned short)f2bf(v.w);
        ((ushort4*)hp)[t] = o;
        aggz[t] = make_ushort4(0, 0, 0, 0);              // 6.4M bf16 = 1.6M ushort4 exactly
        return;
    }
    int t = (blockIdx.x - 6250) * blockDim.x + threadIdx.x;  // 385 blocks: 6*16384 + 128
    if (t >= 98304) {
        int d = t - 98304;
        if (d < 128) w1c_out[d] = (unsigned short)f2bf(W1[d * 257 + 256]);
        return;
    }
    int mat = t >> 14;
    int r = t & 16383;
    int j = r & 7;
    int lane = (r >> 3) & 63;
    int f = r >> 9;            // 0..31
    int ks = f & 3, nt = f >> 2;
    int n = nt * 16 + (lane & 15);
    int k = ks * 32 + (lane >> 4) * 8 + j;
    float v;
    switch (mat) {
        case 0: v = W1[n * 257 + k];        break;  // W1a (vs h_sender)
        case 1: v = W1[n * 257 + 128 + k];  break;  // W1b (vs h_receiver)
        case 2: v = W2[n * 128 + k];        break;  // W2
        case 3: v = U1[n * 256 + k];        break;  // U1a (vs h)
        case 4: v = U1[n * 256 + 128 + k];  break;  // U1b (vs agg)
        default: v = U2[n * 128 + k];       break;  // U2
    }
    packs[t] = (unsigned short)f2bf(v);
}

// ---- prep_g: per-node G1a = h*W1a^T + b1, G1b = h*W1b^T, stored bf16 [NN][256] ----
__global__ __launch_bounds__(256, 2) void prep_g_kernel(
    const unsigned short* __restrict__ hp,
    const bf16x8* __restrict__ w1a_pack,
    const bf16x8* __restrict__ w1b_pack,
    const float* __restrict__ b1,
    unsigned short* __restrict__ G)
{
    const int tid = threadIdx.x;
    const int wave = tid >> 6, lane = tid & 63;
    const int quad = lane >> 4, l15 = lane & 15;
    const int nbase = blockIdx.x * 64 + wave * 16;

    int n = nbase + l15;
    int nrow = n < NN ? n : NN - 1;

    bf16x8 ah[4];
    #pragma unroll
    for (int ks = 0; ks < 4; ks++)
        ah[ks] = *(const bf16x8*)(hp + (size_t)nrow * DD + ks * 32 + quad * 8);

    f32x4 acca[8], accb[8];
    #pragma unroll
    for (int nt = 0; nt < 8; nt++) {
        acca[nt] = f32x4{0.f, 0.f, 0.f, 0.f};
        accb[nt] = f32x4{0.f, 0.f, 0.f, 0.f};
    }

    #pragma unroll
    for (int ks = 0; ks < 4; ks++) {
        #pragma unroll
        for (int nt = 0; nt < 8; nt++)
            acca[nt] = __builtin_amdgcn_mfma_f32_16x16x32_bf16(
                ah[ks], w1a_pack[(nt * 4 + ks) * 64 + lane], acca[nt], 0, 0, 0);
        #pragma unroll
        for (int nt = 0; nt < 8; nt++)
            accb[nt] = __builtin_amdgcn_mfma_f32_16x16x32_bf16(
                ah[ks], w1b_pack[(nt * 4 + ks) * 64 + lane], accb[nt], 0, 0, 0);
    }

    #pragma unroll
    for (int nt = 0; nt < 8; nt++) {
        int d = nt * 16 + l15;
        float b1v = b1[d];
        #pragma unroll
        for (int r = 0; r < 4; r++) {
            int n2 = nbase + quad * 4 + r;
            if (n2 < NN) {
                G[(size_t)n2 * 256 + d]       = (unsigned short)f2bf(acca[nt][r] + b1v);
                G[(size_t)n2 * 256 + 128 + d] = (unsigned short)f2bf(accb[nt][r]);
            }
        }
    }
}

// ---- edge kernel: gather G -> silu (A/B-frag) -> TRANSPOSED W2 MFMA -> pk bf16 atomics ----
// (256,3) is the empirically clean point: R4 ran 84 VGPR zero-spill; caps <=128
// (256,4/5/6) all collapsed the allocator to 40-64 regs + 200-450 MB scratch traffic.
__global__ __launch_bounds__(256, 3) void edge_kernel(
    const unsigned short* __restrict__ G,      // [NN][256] bf16: [G1a+b1 | G1b]
    const float* __restrict__ coords,          // [NN][3]
    const int* __restrict__ ei,                // [2][EE] int32
    const bf16x8* __restrict__ w2_pack,        // 32 KB
    const unsigned short* __restrict__ w1c,    // [128] bf16, k-order
    const float* __restrict__ b2,
    unsigned short* __restrict__ aggb)         // [NN][128] bf16, pk-atomic accumulated
{
    __shared__ int send_s[4][64];
    __shared__ int recv_s[4][64];
    __shared__ float dist_s[4][64];

    const int tid = threadIdx.x;
    const int wave = tid >> 6, lane = tid & 63;
    const int quad = lane >> 4, l15 = lane & 15;
    const int ebase = blockIdx.x * 256 + wave * 64;

    {
        int e = ebase + lane;
        int s = ei[e];
        int r = ei[EE + e];
        send_s[wave][lane] = s;
        recv_s[wave][lane] = r;
        float dx = coords[3 * s + 0] - coords[3 * r + 0];
        float dy = coords[3 * s + 1] - coords[3 * r + 1];
        float dz = coords[3 * s + 2] - coords[3 * r + 2];
        dist_s[wave][lane] = sqrtf(dx * dx + dy * dy + dz * dz);
    }
    __syncthreads();

    // per-lane w1c fragment (bf16, 16 VGPRs) at k = ks*32 + quad*8 + j
    bf16x8 w1cf[4];
    #pragma unroll
    for (int ks = 0; ks < 4; ks++)
        w1cf[ks] = *(const bf16x8*)(w1c + ks * 32 + quad * 8);

    // tile-0 gathers (cached: G rows are reused ~16x across edges)
    bf16x8 ga[4], gb[4];
    {
        int sr = send_s[wave][l15], rr = recv_s[wave][l15];
        #pragma unroll
        for (int ks = 0; ks < 4; ks++) {
            ga[ks] = *(const bf16x8*)(G + (size_t)sr * 256 + ks * 32 + quad * 8);
            gb[ks] = *(const bf16x8*)(G + (size_t)rr * 256 + 128 + ks * 32 + quad * 8);
        }
    }

    #pragma unroll
    for (int mt = 0; mt < 4; mt++) {
        float dist = dist_s[wave][mt * 16 + l15];   // lane l15 = edge in frag layout
        int recvr  = recv_s[wave][mt * 16 + l15];   // ONE receiver per lane (C^T layout)

        // layer-1 epilogue in registers; m1f doubles as the MFMA B-fragment
        bf16x8 m1f[4];
        #pragma unroll
        for (int ks = 0; ks < 4; ks++) {
            #pragma unroll
            for (int j = 0; j < 8; j++) {
                float pre = bf2f(ga[ks][j]) + bf2f(gb[ks][j]) + dist * bf2f(w1cf[ks][j]);
                m1f[ks][j] = f2bf(fast_silu(pre));
            }
        }

        // prefetch next tile's gathers BEFORE issuing this tile's atomics
        if (mt < 3) {
            int sr2 = send_s[wave][(mt + 1) * 16 + l15];
            int rr2 = recv_s[wave][(mt + 1) * 16 + l15];
            #pragma unroll
            for (int ks = 0; ks < 4; ks++) {
                ga[ks] = *(const bf16x8*)(G + (size_t)sr2 * 256 + ks * 32 + quad * 8);
                gb[ks] = *(const bf16x8*)(G + (size_t)rr2 * 256 + 128 + ks * 32 + quad * 8);
            }
        }

        // layer 2 TRANSPOSED: acc2 = W2 * M1^T  (C row = d, col = edge)
        // A-frag and B-frag share the same per-lane storage, so w2_pack/m1f are reused as-is.
        f32x4 acc2[8];
        #pragma unroll
        for (int nt = 0; nt < 8; nt++) acc2[nt] = f32x4{0.f, 0.f, 0.f, 0.f};
        #pragma unroll
        for (int ks = 0; ks < 4; ks++)
            #pragma unroll
            for (int nt = 0; nt < 8; nt++)
                acc2[nt] = __builtin_amdgcn_mfma_f32_16x16x32_bf16(
                    w2_pack[(nt * 4 + ks) * 64 + lane], m1f[ks], acc2[nt], 0, 0, 0);

        // epilogue 2: silu(acc2 + b2), packed-bf16 atomic add.
        // Per lane: edge = mt*16+l15 (fixed receiver), d = nt*16 + quad*4 + r.
        unsigned short* aggrow = aggb + (size_t)recvr * DD;
        #pragma unroll
        for (int nt = 0; nt < 8; nt++) {
            f32x4 b2q = *(const f32x4*)(b2 + nt * 16 + quad * 4);
            s16x2 p01, p23;
            p01[0] = f2bf(fast_silu(acc2[nt][0] + b2q[0]));
            p01[1] = f2bf(fast_silu(acc2[nt][1] + b2q[1]));
            p23[0] = f2bf(fast_silu(acc2[nt][2] + b2q[2]));
            p23[1] = f2bf(fast_silu(acc2[nt][3] + b2q[3]));
            __builtin_amdgcn_global_atomic_fadd_v2bf16(
                (s16x2*)(aggrow + nt * 16 + quad * 4), p01);
            __builtin_amdgcn_global_atomic_fadd_v2bf16(
                (s16x2*)(aggrow + nt * 16 + quad * 4 + 2), p23);
        }
    }
}

// ---- node kernel: out = h + U2*silu(U1a*h + U1b*agg + c1) + c2 ----
__global__ __launch_bounds__(256, 4) void node_kernel(
    const unsigned short* __restrict__ hp,
    const float* __restrict__ hf,
    const unsigned short* __restrict__ aggb,   // bf16 [NN][128]
    const bf16x8* __restrict__ u1a_pack,
    const bf16x8* __restrict__ u1b_pack,
    const bf16x8* __restrict__ u2_pack,
    const float* __restrict__ c1,
    const float* __restrict__ c2,
    float* __restrict__ out)
{
    __shared__ unsigned short u1s[4][16][136];

    const int tid = threadIdx.x;
    const int wave = tid >> 6, lane = tid & 63;
    const int quad = lane >> 4, l15 = lane & 15;
    const int nbase = blockIdx.x * 64 + wave * 16;

    int n = nbase + l15;
    int nrow = n < NN ? n : NN - 1;

    float c1v[8];
    #pragma unroll
    for (int nt = 0; nt < 8; nt++) c1v[nt] = c1[nt * 16 + l15];

    bf16x8 ah[4], ag[4];
    #pragma unroll
    for (int ks = 0; ks < 4; ks++) {
        ah[ks] = *(const bf16x8*)(hp + (size_t)nrow * DD + ks * 32 + quad * 8);
        ag[ks] = *(const bf16x8*)(aggb + (size_t)nrow * DD + ks * 32 + quad * 8);
    }

    f32x4 acc[8];
    #pragma unroll
    for (int nt = 0; nt < 8; nt++) acc[nt] = f32x4{0.f, 0.f, 0.f, 0.f};

    #pragma unroll
    for (int ks = 0; ks < 4; ks++) {
        #pragma unroll
        for (int nt = 0; nt < 8; nt++)
            acc[nt] = __builtin_amdgcn_mfma_f32_16x16x32_bf16(
                ah[ks], u1a_pack[(nt * 4 + ks) * 64 + lane], acc[nt], 0, 0, 0);
        #pragma unroll
        for (int nt = 0; nt < 8; nt++)
            acc[nt] = __builtin_amdgcn_mfma_f32_16x16x32_bf16(
                ag[ks], u1b_pack[(nt * 4 + ks) * 64 + lane], acc[nt], 0, 0, 0);
    }

    #pragma unroll
    for (int nt = 0; nt < 8; nt++) {
        int d = nt * 16 + l15;
        #pragma unroll
        for (int r = 0; r < 4; r++) {
            float pre = acc[nt][r] + c1v[nt];
            u1s[wave][quad * 4 + r][d] = (unsigned short)f2bf(fast_silu(pre));
        }
    }
    asm volatile("s_waitcnt lgkmcnt(0)" ::: "memory");

    bf16x8 a2[4];
    #pragma unroll
    for (int ks = 0; ks < 4; ks++)
        a2[ks] = *(const bf16x8*)(&u1s[wave][l15][ks * 32 + quad * 8]);

    f32x4 acc2[8];
    #pragma unroll
    for (int nt = 0; nt < 8; nt++) acc2[nt] = f32x4{0.f, 0.f, 0.f, 0.f};

    #pragma unroll
    for (int ks = 0; ks < 4; ks++)
        #pragma unroll
        for (int nt = 0; nt < 8; nt++)
            acc2[nt] = __builtin_amdgcn_mfma_f32_16x16x32_bf16(
                a2[ks], u2_pack[(nt * 4 + ks) * 64 + lane], acc2[nt], 0, 0, 0);

    #pragma unroll
    for (int nt = 0; nt < 8; nt++) {
        int d = nt * 16 + l15;
        float c2v = c2[d];
        #pragma unroll
        for (int r = 0; r < 4; r++) {
            int n2 = nbase + quad * 4 + r;
            if (n2 < NN) {
                size_t idx = (size_t)n2 * DD + d;
                out[idx] = hf[idx] + acc2[nt][r] + c2v;
            }
        }
    }
}

extern "C" void kernel_launch(void* const* d_in, const int* in_sizes, int n_in,
                              void* d_out, int out_size, void* d_ws, size_t ws_size,
                              hipStream_t stream) {
    const float* h      = (const float*)d_in[0];
    const float* coords = (const float*)d_in[1];
    const int* ei       = (const int*)d_in[2];   // int64 in reference -> int32 from harness
    const float* W1 = (const float*)d_in[3];
    const float* b1 = (const float*)d_in[4];
    const float* W2 = (const float*)d_in[5];
    const float* b2 = (const float*)d_in[6];
    const float* U1 = (const float*)d_in[7];
    const float* c1 = (const float*)d_in[8];
    const float* U2 = (const float*)d_in[9];
    const float* c2 = (const float*)d_in[10];
    float* out = (float*)d_out;

    char* ws = (char*)d_ws;
    unsigned short* aggb = (unsigned short*)ws;                 // 12,800,000 B bf16 [NN][128]
    unsigned short* hp = (unsigned short*)(ws + 12800000);      // 12,800,000 B bf16 h
    unsigned short* packs = (unsigned short*)(ws + 25600000);   // 196,608 B packed weights
    unsigned short* w1c = (unsigned short*)(ws + 25800000);     // 256 B bf16
    unsigned short* G = (unsigned short*)(ws + 25900032);       // 25,600,000 B bf16 [NN][256]
    const bf16x8* w1a = (const bf16x8*)(packs);
    const bf16x8* w1b = (const bf16x8*)(packs + 16384);
    const bf16x8* w2p = (const bf16x8*)(packs + 32768);
    const bf16x8* u1a = (const bf16x8*)(packs + 49152);
    const bf16x8* u1b = (const bf16x8*)(packs + 65536);
    const bf16x8* u2p = (const bf16x8*)(packs + 81920);

    prep_kernel<<<6635, 256, 0, stream>>>(h, hp, (ushort4*)aggb, W1, W2, U1, U2, packs, w1c);
    prep_g_kernel<<<(NN + 63) / 64, 256, 0, stream>>>(hp, w1a, w1b, b1, G);
    edge_kernel<<<EE / 256, 256, 0, stream>>>(G, coords, ei, w2p, w1c, b2, aggb);
    node_kernel<<<(NN + 63) / 64, 256, 0, stream>>>(hp, h, aggb, u1a, u1b, u2p, c1, c2, out);
}

// Round 9
// 513.468 us; speedup vs baseline: 1.6155x; 1.6155x over previous
//
#include <hip/hip_runtime.h>
#include <hip/hip_bf16.h>

#define NN 50000
#define EE 800000
#define DD 128

typedef __attribute__((ext_vector_type(8))) short bf16x8;
typedef __attribute__((ext_vector_type(4))) float f32x4;

__device__ __forceinline__ short f2bf(float f) {
    __hip_bfloat16 h = __float2bfloat16(f);
    return __builtin_bit_cast(short, h);
}

__device__ __forceinline__ float bf2f(short s) {
    unsigned int u = ((unsigned int)(unsigned short)s) << 16;
    return __builtin_bit_cast(float, u);
}

__device__ __forceinline__ float fast_silu(float x) {
    return x / (1.0f + __expf(-x));
}

// ---- prep: h->bf16 + zero agg (blocks 0..6249), pack weights (blocks 6250..6634), w1c bf16 ----
__global__ void prep_kernel(const float* __restrict__ h, unsigned short* __restrict__ hp,
                            float4* __restrict__ agg4,
                            const float* __restrict__ W1, const float* __restrict__ W2,
                            const float* __restrict__ U1, const float* __restrict__ U2,
                            unsigned short* __restrict__ packs,
                            unsigned short* __restrict__ w1c_out) {
    if (blockIdx.x < 6250) {
        int t = blockIdx.x * blockDim.x + threadIdx.x;   // 1.6M threads exactly
        float4 v = ((const float4*)h)[t];
        ushort4 o;
        o.x = (unsigned short)f2bf(v.x);
        o.y = (unsigned short)f2bf(v.y);
        o.z = (unsigned short)f2bf(v.z);
        o.w = (unsigned short)f2bf(v.w);
        ((ushort4*)hp)[t] = o;
        agg4[t] = make_float4(0.f, 0.f, 0.f, 0.f);
        return;
    }
    int t = (blockIdx.x - 6250) * blockDim.x + threadIdx.x;  // 385 blocks: 6*16384 + 128
    if (t >= 98304) {
        int d = t - 98304;
        if (d < 128) w1c_out[d] = (unsigned short)f2bf(W1[d * 257 + 256]);
        return;
    }
    int mat = t >> 14;
    int r = t & 16383;
    int j = r & 7;
    int lane = (r >> 3) & 63;
    int f = r >> 9;            // 0..31
    int ks = f & 3, nt = f >> 2;
    int n = nt * 16 + (lane & 15);
    int k = ks * 32 + (lane >> 4) * 8 + j;
    float v;
    switch (mat) {
        case 0: v = W1[n * 257 + k];        break;  // W1a (vs h_sender)
        case 1: v = W1[n * 257 + 128 + k];  break;  // W1b (vs h_receiver)
        case 2: v = W2[n * 128 + k];        break;  // W2
        case 3: v = U1[n * 256 + k];        break;  // U1a (vs h)
        case 4: v = U1[n * 256 + 128 + k];  break;  // U1b (vs agg)
        default: v = U2[n * 128 + k];       break;  // U2
    }
    packs[t] = (unsigned short)f2bf(v);
}

// ---- prep_g: per-node G1a = h*W1a^T + b1, G1b = h*W1b^T, stored bf16 [NN][256] ----
__global__ __launch_bounds__(256, 2) void prep_g_kernel(
    const unsigned short* __restrict__ hp,
    const bf16x8* __restrict__ w1a_pack,
    const bf16x8* __restrict__ w1b_pack,
    const float* __restrict__ b1,
    unsigned short* __restrict__ G)
{
    const int tid = threadIdx.x;
    const int wave = tid >> 6, lane = tid & 63;
    const int quad = lane >> 4, l15 = lane & 15;
    const int nbase = blockIdx.x * 64 + wave * 16;

    int n = nbase + l15;
    int nrow = n < NN ? n : NN - 1;

    bf16x8 ah[4];
    #pragma unroll
    for (int ks = 0; ks < 4; ks++)
        ah[ks] = *(const bf16x8*)(hp + (size_t)nrow * DD + ks * 32 + quad * 8);

    f32x4 acca[8], accb[8];
    #pragma unroll
    for (int nt = 0; nt < 8; nt++) {
        acca[nt] = f32x4{0.f, 0.f, 0.f, 0.f};
        accb[nt] = f32x4{0.f, 0.f, 0.f, 0.f};
    }

    #pragma unroll
    for (int ks = 0; ks < 4; ks++) {
        #pragma unroll
        for (int nt = 0; nt < 8; nt++)
            acca[nt] = __builtin_amdgcn_mfma_f32_16x16x32_bf16(
                ah[ks], w1a_pack[(nt * 4 + ks) * 64 + lane], acca[nt], 0, 0, 0);
        #pragma unroll
        for (int nt = 0; nt < 8; nt++)
            accb[nt] = __builtin_amdgcn_mfma_f32_16x16x32_bf16(
                ah[ks], w1b_pack[(nt * 4 + ks) * 64 + lane], accb[nt], 0, 0, 0);
    }

    #pragma unroll
    for (int nt = 0; nt < 8; nt++) {
        int d = nt * 16 + l15;
        float b1v = b1[d];
        #pragma unroll
        for (int r = 0; r < 4; r++) {
            int n2 = nbase + quad * 4 + r;
            if (n2 < NN) {
                G[(size_t)n2 * 256 + d]       = (unsigned short)f2bf(acca[nt][r] + b1v);
                G[(size_t)n2 * 256 + 128 + d] = (unsigned short)f2bf(accb[nt][r]);
            }
        }
    }
}

// ---- edge kernel: gather G slices -> VALU silu (direct A-frag) -> W2 MFMA -> fp32 atomics ----
// NO __launch_bounds__: every explicit cap <=128 (R5/R6/R7: (256,6)/(256,5)/(256,4)) made the
// allocator collapse to 40-64 arch VGPRs + 200-450 MB scratch spill traffic. Uncapped, the
// compiler picks its own no-spill allocation. (256,3) was the only clean capped point (R4, 366us).
// Atomic layout: lane owns d=nt*16+l15, rows quad*4+r -> per instruction 4 coalesced 64B lines.
// (R8's C^T layout: 1 line/lane, 64 lines/instruction -> 687us. Coalescing >> payload size.)
__global__ void edge_kernel(
    const unsigned short* __restrict__ G,      // [NN][256] bf16: [G1a+b1 | G1b]
    const float* __restrict__ coords,          // [NN][3]
    const int* __restrict__ ei,                // [2][EE] int32
    const bf16x8* __restrict__ w2_pack,        // 32 KB
    const unsigned short* __restrict__ w1c,    // [128] bf16, k-order
    const float* __restrict__ b2,
    float* __restrict__ agg)
{
    __shared__ int send_s[4][64];
    __shared__ int recv_s[4][64];
    __shared__ float dist_s[4][64];

    const int tid = threadIdx.x;
    const int wave = tid >> 6, lane = tid & 63;
    const int quad = lane >> 4, l15 = lane & 15;
    const int ebase = blockIdx.x * 256 + wave * 64;

    {
        int e = ebase + lane;
        int s = ei[e];
        int r = ei[EE + e];
        send_s[wave][lane] = s;
        recv_s[wave][lane] = r;
        float dx = coords[3 * s + 0] - coords[3 * r + 0];
        float dy = coords[3 * s + 1] - coords[3 * r + 1];
        float dz = coords[3 * s + 2] - coords[3 * r + 2];
        dist_s[wave][lane] = sqrtf(dx * dx + dy * dy + dz * dz);
    }
    __syncthreads();

    // per-lane w1c fragment (bf16, 16 VGPRs) at k = ks*32 + quad*8 + j
    bf16x8 w1cf[4];
    #pragma unroll
    for (int ks = 0; ks < 4; ks++)
        w1cf[ks] = *(const bf16x8*)(w1c + ks * 32 + quad * 8);
    float b2f[8];
    #pragma unroll
    for (int nt = 0; nt < 8; nt++) b2f[nt] = b2[nt * 16 + l15];

    // tile-0 gathers (cached: G rows are reused ~16x across edges)
    bf16x8 ga[4], gb[4];
    {
        int sr = send_s[wave][l15], rr = recv_s[wave][l15];
        #pragma unroll
        for (int ks = 0; ks < 4; ks++) {
            ga[ks] = *(const bf16x8*)(G + (size_t)sr * 256 + ks * 32 + quad * 8);
            gb[ks] = *(const bf16x8*)(G + (size_t)rr * 256 + 128 + ks * 32 + quad * 8);
        }
    }

    #pragma unroll
    for (int mt = 0; mt < 4; mt++) {
        float dist = dist_s[wave][mt * 16 + l15];   // lane l15 = edge row in A-layout

        // layer-1 epilogue in registers, directly in A-fragment layout
        bf16x8 m1f[4];
        #pragma unroll
        for (int ks = 0; ks < 4; ks++) {
            #pragma unroll
            for (int j = 0; j < 8; j++) {
                float pre = bf2f(ga[ks][j]) + bf2f(gb[ks][j]) + dist * bf2f(w1cf[ks][j]);
                m1f[ks][j] = f2bf(fast_silu(pre));
            }
        }

        // prefetch next tile's gathers BEFORE issuing this tile's atomics
        // (keeps the vmcnt FIFO such that consuming these loads never waits on atomic stores)
        if (mt < 3) {
            int sr2 = send_s[wave][(mt + 1) * 16 + l15];
            int rr2 = recv_s[wave][(mt + 1) * 16 + l15];
            #pragma unroll
            for (int ks = 0; ks < 4; ks++) {
                ga[ks] = *(const bf16x8*)(G + (size_t)sr2 * 256 + ks * 32 + quad * 8);
                gb[ks] = *(const bf16x8*)(G + (size_t)rr2 * 256 + 128 + ks * 32 + quad * 8);
            }
        }

        // layer 2: acc2 = M1 * W2^T
        f32x4 acc2[8];
        #pragma unroll
        for (int nt = 0; nt < 8; nt++) acc2[nt] = f32x4{0.f, 0.f, 0.f, 0.f};
        #pragma unroll
        for (int ks = 0; ks < 4; ks++)
            #pragma unroll
            for (int nt = 0; nt < 8; nt++)
                acc2[nt] = __builtin_amdgcn_mfma_f32_16x16x32_bf16(
                    m1f[ks], w2_pack[(nt * 4 + ks) * 64 + lane], acc2[nt], 0, 0, 0);

        // epilogue 2: silu(acc2 + b2), atomic scatter-add (C-layout: row=quad*4+r)
        int rrr[4];
        #pragma unroll
        for (int r = 0; r < 4; r++) rrr[r] = recv_s[wave][mt * 16 + quad * 4 + r];
        #pragma unroll
        for (int nt = 0; nt < 8; nt++) {
            #pragma unroll
            for (int r = 0; r < 4; r++) {
                float v = fast_silu(acc2[nt][r] + b2f[nt]);
                unsafeAtomicAdd(&agg[(size_t)rrr[r] * DD + nt * 16 + l15], v);
            }
        }
    }
}

// ---- node kernel: out = h + U2*silu(U1a*h + U1b*agg + c1) + c2 ----
__global__ __launch_bounds__(256, 4) void node_kernel(
    const unsigned short* __restrict__ hp,
    const float* __restrict__ hf,
    const float* __restrict__ agg,
    const bf16x8* __restrict__ u1a_pack,
    const bf16x8* __restrict__ u1b_pack,
    const bf16x8* __restrict__ u2_pack,
    const float* __restrict__ c1,
    const float* __restrict__ c2,
    float* __restrict__ out)
{
    __shared__ unsigned short u1s[4][16][136];

    const int tid = threadIdx.x;
    const int wave = tid >> 6, lane = tid & 63;
    const int quad = lane >> 4, l15 = lane & 15;
    const int nbase = blockIdx.x * 64 + wave * 16;

    int n = nbase + l15;
    int nrow = n < NN ? n : NN - 1;

    float c1v[8];
    #pragma unroll
    for (int nt = 0; nt < 8; nt++) c1v[nt] = c1[nt * 16 + l15];

    bf16x8 ah[4], ag[4];
    #pragma unroll
    for (int ks = 0; ks < 4; ks++) {
        ah[ks] = *(const bf16x8*)(hp + (size_t)nrow * DD + ks * 32 + quad * 8);
        const float* ap = agg + (size_t)nrow * DD + ks * 32 + quad * 8;
        f32x4 g0 = *(const f32x4*)ap;
        f32x4 g1 = *(const f32x4*)(ap + 4);
        bf16x8 t;
        t[0] = f2bf(g0[0]); t[1] = f2bf(g0[1]); t[2] = f2bf(g0[2]); t[3] = f2bf(g0[3]);
        t[4] = f2bf(g1[0]); t[5] = f2bf(g1[1]); t[6] = f2bf(g1[2]); t[7] = f2bf(g1[3]);
        ag[ks] = t;
    }

    f32x4 acc[8];
    #pragma unroll
    for (int nt = 0; nt < 8; nt++) acc[nt] = f32x4{0.f, 0.f, 0.f, 0.f};

    #pragma unroll
    for (int ks = 0; ks < 4; ks++) {
        #pragma unroll
        for (int nt = 0; nt < 8; nt++)
            acc[nt] = __builtin_amdgcn_mfma_f32_16x16x32_bf16(
                ah[ks], u1a_pack[(nt * 4 + ks) * 64 + lane], acc[nt], 0, 0, 0);
        #pragma unroll
        for (int nt = 0; nt < 8; nt++)
            acc[nt] = __builtin_amdgcn_mfma_f32_16x16x32_bf16(
                ag[ks], u1b_pack[(nt * 4 + ks) * 64 + lane], acc[nt], 0, 0, 0);
    }

    #pragma unroll
    for (int nt = 0; nt < 8; nt++) {
        int d = nt * 16 + l15;
        #pragma unroll
        for (int r = 0; r < 4; r++) {
            float pre = acc[nt][r] + c1v[nt];
            u1s[wave][quad * 4 + r][d] = (unsigned short)f2bf(fast_silu(pre));
        }
    }
    asm volatile("s_waitcnt lgkmcnt(0)" ::: "memory");

    bf16x8 a2[4];
    #pragma unroll
    for (int ks = 0; ks < 4; ks++)
        a2[ks] = *(const bf16x8*)(&u1s[wave][l15][ks * 32 + quad * 8]);

    f32x4 acc2[8];
    #pragma unroll
    for (int nt = 0; nt < 8; nt++) acc2[nt] = f32x4{0.f, 0.f, 0.f, 0.f};

    #pragma unroll
    for (int ks = 0; ks < 4; ks++)
        #pragma unroll
        for (int nt = 0; nt < 8; nt++)
            acc2[nt] = __builtin_amdgcn_mfma_f32_16x16x32_bf16(
                a2[ks], u2_pack[(nt * 4 + ks) * 64 + lane], acc2[nt], 0, 0, 0);

    #pragma unroll
    for (int nt = 0; nt < 8; nt++) {
        int d = nt * 16 + l15;
        float c2v = c2[d];
        #pragma unroll
        for (int r = 0; r < 4; r++) {
            int n2 = nbase + quad * 4 + r;
            if (n2 < NN) {
                size_t idx = (size_t)n2 * DD + d;
                out[idx] = hf[idx] + acc2[nt][r] + c2v;
            }
        }
    }
}

extern "C" void kernel_launch(void* const* d_in, const int* in_sizes, int n_in,
                              void* d_out, int out_size, void* d_ws, size_t ws_size,
                              hipStream_t stream) {
    const float* h      = (const float*)d_in[0];
    const float* coords = (const float*)d_in[1];
    const int* ei       = (const int*)d_in[2];   // int64 in reference -> int32 from harness
    const float* W1 = (const float*)d_in[3];
    const float* b1 = (const float*)d_in[4];
    const float* W2 = (const float*)d_in[5];
    const float* b2 = (const float*)d_in[6];
    const float* U1 = (const float*)d_in[7];
    const float* c1 = (const float*)d_in[8];
    const float* U2 = (const float*)d_in[9];
    const float* c2 = (const float*)d_in[10];
    float* out = (float*)d_out;

    char* ws = (char*)d_ws;
    float* agg = (float*)ws;                                    // 25,600,000 B fp32
    unsigned short* hp = (unsigned short*)(ws + 25600000);      // 12,800,000 B bf16 h
    unsigned short* packs = (unsigned short*)(ws + 38400000);   // 196,608 B packed weights
    unsigned short* w1c = (unsigned short*)(ws + 38600000);     // 256 B bf16
    unsigned short* G = (unsigned short*)(ws + 38700032);       // 25,600,000 B bf16 [NN][256]
    const bf16x8* w1a = (const bf16x8*)(packs);
    const bf16x8* w1b = (const bf16x8*)(packs + 16384);
    const bf16x8* w2p = (const bf16x8*)(packs + 32768);
    const bf16x8* u1a = (const bf16x8*)(packs + 49152);
    const bf16x8* u1b = (const bf16x8*)(packs + 65536);
    const bf16x8* u2p = (const bf16x8*)(packs + 81920);

    prep_kernel<<<6635, 256, 0, stream>>>(h, hp, (float4*)agg, W1, W2, U1, U2, packs, w1c);
    prep_g_kernel<<<(NN + 63) / 64, 256, 0, stream>>>(hp, w1a, w1b, b1, G);
    edge_kernel<<<EE / 256, 256, 0, stream>>>(G, coords, ei, w2p, w1c, b2, agg);
    node_kernel<<<(NN + 63) / 64, 256, 0, stream>>>(hp, h, agg, u1a, u1b, u2p, c1, c2, out);
}